// Round 1
// baseline (304.878 us; speedup 1.0000x reference)
//
#include <hip/hip_runtime.h>
#include <hip/hip_bf16.h>

// Problem constants
#define NUM_BINS 15
#define POOL_W 3
#define N_CTX 32
#define C_IMG 3
#define HGT 512
#define WID 512
#define HW (HGT * WID)

#define TS 32          // output tile (TS x TS)
#define PT 34          // y_probs tile (TS + 2)
#define IT 36          // input tile (TS + 4)

static __device__ __forceinline__ float sigmoidf_(float x) {
    return 1.0f / (1.0f + expf(-x));
}

// ---------------------------------------------------------------------------
// Kernel 0: sumLab[p] = sum_n labs[n][p]; also zero the global histogram.
// ---------------------------------------------------------------------------
__global__ __launch_bounds__(256) void k_sumlab(const float* __restrict__ labs,
                                                float* __restrict__ sumLab,
                                                unsigned int* __restrict__ hist) {
    int p = blockIdx.x * 256 + threadIdx.x;
    if (blockIdx.x == 0 && threadIdx.x < 2 * NUM_BINS) hist[threadIdx.x] = 0u;
    if (p < HW) {
        float s = 0.0f;
        #pragma unroll
        for (int n = 0; n < N_CTX; ++n) s += labs[(size_t)n * HW + p];
        sumLab[p] = s;
    }
}

// ---------------------------------------------------------------------------
// Kernel 1: fused conv -> sigmoid -> 3x3 count-valid pooling -> histogram.
// grid = (W/TS, H/TS, N_CTX), block = 256.
// ---------------------------------------------------------------------------
__global__ __launch_bounds__(256) void k_main(const float* __restrict__ imgs,
                                              const float* __restrict__ labs,
                                              const float* __restrict__ sumLab,
                                              const float* __restrict__ w_img,
                                              const float* __restrict__ w_lab,
                                              unsigned int* __restrict__ hist) {
    __shared__ float s_in[4][IT][IT + 1];   // img0..2, loo plane
    __shared__ float s_lab[IT][IT + 1];
    __shared__ float s_p[PT][PT + 1];
    __shared__ unsigned int s_h[2 * NUM_BINS];

    const int tid = threadIdx.x;
    const int n = blockIdx.z;
    const int y0 = blockIdx.y * TS;
    const int x0 = blockIdx.x * TS;
    const float BIN_W = (float)(1.0 / 15.0);
    const float inv31 = 1.0f / (float)(N_CTX - 1);

    // Weights (uniform -> compiler can scalarize)
    float wi[C_IMG][9];
    float wl[9];
    #pragma unroll
    for (int c = 0; c < C_IMG; ++c)
        #pragma unroll
        for (int k = 0; k < 9; ++k) wi[c][k] = w_img[c * 9 + k];
    #pragma unroll
    for (int k = 0; k < 9; ++k) wl[k] = w_lab[k];

    if (tid < 2 * NUM_BINS) s_h[tid] = 0u;

    const float* img_n = imgs + (size_t)n * C_IMG * HW;
    const float* lab_n = labs + (size_t)n * HW;

    // ---- stage halo'd input planes (zero outside image: SAME zero padding) ----
    for (int idx = tid; idx < IT * IT; idx += 256) {
        int iy = idx / IT, ix = idx - iy * IT;
        int gy = y0 - 2 + iy, gx = x0 - 2 + ix;
        bool in = (gy >= 0) & (gy < HGT) & (gx >= 0) & (gx < WID);
        int g = gy * WID + gx;
        float l  = in ? lab_n[g]  : 0.0f;
        float sl = in ? sumLab[g] : 0.0f;
        s_lab[iy][ix] = l;
        s_in[3][iy][ix] = (sl - l) * inv31;   // loo_mean plane (0 outside)
        #pragma unroll
        for (int c = 0; c < C_IMG; ++c)
            s_in[c][iy][ix] = in ? img_n[(size_t)c * HW + g] : 0.0f;
    }
    __syncthreads();

    // ---- y_probs ring: conv3x3 (cross-correlation) + sigmoid ----
    for (int idx = tid; idx < PT * PT; idx += 256) {
        int py = idx / PT, px = idx - py * PT;
        float z = 0.0f;
        #pragma unroll
        for (int di = 0; di < 3; ++di)
            #pragma unroll
            for (int dj = 0; dj < 3; ++dj) {
                z += wi[0][di * 3 + dj] * s_in[0][py + di][px + dj];
                z += wi[1][di * 3 + dj] * s_in[1][py + di][px + dj];
                z += wi[2][di * 3 + dj] * s_in[2][py + di][px + dj];
                z += wl[di * 3 + dj]    * s_in[3][py + di][px + dj];
            }
        s_p[py][px] = sigmoidf_(z);
    }
    __syncthreads();

    // ---- 3x3 pooling (count_include_pad=False) + binning + LDS histogram ----
    for (int idx = tid; idx < TS * TS; idx += 256) {
        int oy = idx / TS, ox = idx - oy * TS;
        int gy = y0 + oy, gx = x0 + ox;
        float sum = 0.0f;
        int cnt = 0;
        #pragma unroll
        for (int dh = -1; dh <= 1; ++dh)
            #pragma unroll
            for (int dw = -1; dw <= 1; ++dw) {
                int ny = gy + dh, nx = gx + dw;
                if (ny >= 0 && ny < HGT && nx >= 0 && nx < WID) {
                    sum += s_p[oy + 1 + dh][ox + 1 + dw];
                    cnt++;
                }
            }
        float p = sum / (float)cnt;
        int b = (int)(p / BIN_W);
        b = b < 0 ? 0 : (b > NUM_BINS - 1 ? NUM_BINS - 1 : b);
        atomicAdd(&s_h[b], 1u);
        if (s_lab[oy + 2][ox + 2] > 0.5f) atomicAdd(&s_h[NUM_BINS + b], 1u);
    }
    __syncthreads();

    if (tid < 2 * NUM_BINS) {
        unsigned int v = s_h[tid];
        if (v) atomicAdd(&hist[tid], v);
    }
}

// ---------------------------------------------------------------------------
// Kernel 2: bin_freqs + gather for target pixels.
// ---------------------------------------------------------------------------
__global__ __launch_bounds__(256) void k_out(const float* __restrict__ tl,
                                             const unsigned int* __restrict__ hist,
                                             float* __restrict__ out) {
    __shared__ float s_f[NUM_BINS];
    const float BIN_W = (float)(1.0 / 15.0);
    int tid = threadIdx.x;
    if (tid < NUM_BINS) {
        unsigned int c = hist[tid];
        unsigned int p = hist[NUM_BINS + tid];
        s_f[tid] = (c > 0) ? (float)p / (float)c : 0.0f;
    }
    __syncthreads();
    int i = blockIdx.x * 256 + tid;
    if (i < HW) {
        float pr = sigmoidf_(tl[i]);
        int b = (int)(pr / BIN_W);
        b = b < 0 ? 0 : (b > NUM_BINS - 1 ? NUM_BINS - 1 : b);
        out[i] = s_f[b];
    }
}

extern "C" void kernel_launch(void* const* d_in, const int* in_sizes, int n_in,
                              void* d_out, int out_size, void* d_ws, size_t ws_size,
                              hipStream_t stream) {
    const float* imgs   = (const float*)d_in[0];  // [1,32,3,512,512]
    const float* labs   = (const float*)d_in[1];  // [1,32,1,512,512]
    const float* tlog   = (const float*)d_in[2];  // [1,1,512,512]
    const float* w_img  = (const float*)d_in[3];  // [1,3,3,3]
    const float* w_lab  = (const float*)d_in[4];  // [1,1,3,3]
    float* out = (float*)d_out;

    float* sumLab = (float*)d_ws;                       // HW floats (1 MB)
    unsigned int* hist = (unsigned int*)((char*)d_ws + (size_t)HW * sizeof(float)); // 30 uints

    k_sumlab<<<(HW + 255) / 256, 256, 0, stream>>>(labs, sumLab, hist);

    dim3 grid(WID / TS, HGT / TS, N_CTX);
    k_main<<<grid, 256, 0, stream>>>(imgs, labs, sumLab, w_img, w_lab, hist);

    k_out<<<(HW + 255) / 256, 256, 0, stream>>>(tlog, hist, out);
}

// Round 3
// 220.992 us; speedup vs baseline: 1.3796x; 1.3796x over previous
//
#include <hip/hip_runtime.h>
#include <hip/hip_bf16.h>

#define NUM_BINS 15
#define N_CTX 32
#define C_IMG 3
#define HGT 512
#define WID 512
#define HW (HGT * WID)

#define EMITW 60                     // emitted columns per 64-lane strip
#define NSTRIP 9                     // ceil(512/60)
#define SEG 32                       // pooled output rows per wave-unit
#define NSEG (HGT / SEG)             // 16
#define UNITS_PER_N (NSTRIP * NSEG)  // 144
#define TOTAL_UNITS (N_CTX * UNITS_PER_N)  // 4608 waves

// ---------------------------------------------------------------------------
// Kernel 0: sumLab = sum_n labs[n]; zero the global histogram. float4 loads.
// grid = HW/4/256 = 256 blocks.
// ---------------------------------------------------------------------------
__global__ __launch_bounds__(256) void k_sumlab(const float4* __restrict__ labs,
                                                float4* __restrict__ sumLab,
                                                unsigned int* __restrict__ hist) {
    int i = blockIdx.x * 256 + threadIdx.x;
    if (blockIdx.x == 0 && threadIdx.x < 2 * NUM_BINS) hist[threadIdx.x] = 0u;
    float4 s = make_float4(0.f, 0.f, 0.f, 0.f);
    #pragma unroll
    for (int n = 0; n < N_CTX; ++n) {
        float4 v = labs[(size_t)n * (HW / 4) + i];
        s.x += v.x; s.y += v.y; s.z += v.z; s.w += v.w;
    }
    sumLab[i] = s;
}

// ---------------------------------------------------------------------------
// Kernel 1: streaming conv -> sigmoid -> 3x3 valid-count pool -> histogram.
// One wave per (n, strip, seg). No LDS staging, no per-row barriers.
// grid = TOTAL_UNITS/4 = 1152 blocks of 256 threads (4 waves).
// ---------------------------------------------------------------------------
__global__ __launch_bounds__(256) void k_main(const float* __restrict__ imgs,
                                              const float* __restrict__ labs,
                                              const float* __restrict__ sumLab,
                                              const float* __restrict__ w_img,
                                              const float* __restrict__ w_lab,
                                              unsigned int* __restrict__ hist) {
    __shared__ unsigned int sh[2 * NUM_BINS];
    const int tid  = threadIdx.x;
    const int lane = tid & 63;
    const int u    = blockIdx.x * 4 + (tid >> 6);
    const int seg   = u % NSEG;
    const int strip = (u / NSEG) % NSTRIP;
    const int n     = u / UNITS_PER_N;
    const int y0 = seg * SEG;
    const int x  = strip * EMITW + lane - 2;
    const bool xv    = (x >= 0) & (x < WID);
    const bool elane = (lane >= 2) & (lane < 2 + EMITW) & (x < WID);
    const bool col3  = (x != 0) & (x != WID - 1);   // colcnt==3 ?
    const float inv31 = 1.0f / 31.0f;

    if (tid < 2 * NUM_BINS) sh[tid] = 0u;
    __syncthreads();

    // 3x3 weights for 4 source planes (img0..2, loo); uniform -> scalar loads
    float w[4][3][3];
    #pragma unroll
    for (int c = 0; c < 3; ++c)
        #pragma unroll
        for (int i = 0; i < 3; ++i)
            #pragma unroll
            for (int j = 0; j < 3; ++j)
                w[c][i][j] = w_img[c * 9 + i * 3 + j];
    #pragma unroll
    for (int i = 0; i < 3; ++i)
        #pragma unroll
        for (int j = 0; j < 3; ++j)
            w[3][i][j] = w_lab[i * 3 + j];

    const float* p0 = imgs + (size_t)n * C_IMG * HW + (ptrdiff_t)(y0 - 2) * WID + x;
    const float* p1 = p0 + HW;
    const float* p2 = p0 + 2 * HW;
    const float* pl = labs + (size_t)n * HW + (ptrdiff_t)(y0 - 2) * WID + x;
    const float* ps = sumLab + (ptrdiff_t)(y0 - 2) * WID + x;

    // register rings
    float hA2 = 0.f, hA1 = 0.f, hB1 = 0.f;   // conv row-decomposition ring
    float hs2 = 0.f, hs1 = 0.f;              // pooled row-sum ring
    float lab1 = 0.f, lab2 = 0.f;            // center label ring (y_true)
    unsigned int ccnt[NUM_BINS], pcnt[NUM_BINS];
    #pragma unroll
    for (int b = 0; b < NUM_BINS; ++b) { ccnt[b] = 0u; pcnt[b] = 0u; }

    int r = y0 - 2;
    #pragma unroll 4
    for (int it = 0; it < SEG + 4; ++it, ++r) {
        const bool rv = (r >= 0) & (r < HGT);
        const bool lv = rv & xv;
        float v0 = 0.f, v1 = 0.f, v2 = 0.f, lb = 0.f, sl = 0.f;
        if (lv) { v0 = *p0; v1 = *p1; v2 = *p2; lb = *pl; sl = *ps; }
        p0 += WID; p1 += WID; p2 += WID; pl += WID; ps += WID;
        const float v3 = (sl - lb) * inv31;   // leave-one-out mean plane

        // horizontal neighbors via wave shuffles (lanes 0/63 garbage — unused)
        const float m0 = __shfl_up(v0, 1), q0 = __shfl_down(v0, 1);
        const float m1 = __shfl_up(v1, 1), q1 = __shfl_down(v1, 1);
        const float m2 = __shfl_up(v2, 1), q2 = __shfl_down(v2, 1);
        const float m3 = __shfl_up(v3, 1), q3 = __shfl_down(v3, 1);

        // per-kernel-row horizontal convs over all 4 planes
        float hA, hB, hC;
        hA  = w[0][0][0]*m0 + w[0][0][1]*v0 + w[0][0][2]*q0;
        hB  = w[0][1][0]*m0 + w[0][1][1]*v0 + w[0][1][2]*q0;
        hC  = w[0][2][0]*m0 + w[0][2][1]*v0 + w[0][2][2]*q0;
        hA += w[1][0][0]*m1 + w[1][0][1]*v1 + w[1][0][2]*q1;
        hB += w[1][1][0]*m1 + w[1][1][1]*v1 + w[1][1][2]*q1;
        hC += w[1][2][0]*m1 + w[1][2][1]*v1 + w[1][2][2]*q1;
        hA += w[2][0][0]*m2 + w[2][0][1]*v2 + w[2][0][2]*q2;
        hB += w[2][1][0]*m2 + w[2][1][1]*v2 + w[2][1][2]*q2;
        hC += w[2][2][0]*m2 + w[2][2][1]*v2 + w[2][2][2]*q2;
        hA += w[3][0][0]*m3 + w[3][0][1]*v3 + w[3][0][2]*q3;
        hB += w[3][1][0]*m3 + w[3][1][1]*v3 + w[3][1][2]*q3;
        hC += w[3][2][0]*m3 + w[3][2][1]*v3 + w[3][2][2]*q3;

        // z(y=r-1) = hA(r-2) + hB(r-1) + hC(r)
        const float z = hA2 + hB1 + hC;
        hA2 = hA1; hA1 = hA; hB1 = hB;

        const int y = r - 1;
        const bool yv = (y >= 0) & (y < HGT);
        const float pr = 1.0f / (1.0f + __expf(-z));
        const float pc = (yv & xv) ? pr : 0.f;   // zero outside image
        const float hs = __shfl_up(pc, 1) + pc + __shfl_down(pc, 1);

        // pooled(yc=r-2) = hs(yc-1)+hs(yc)+hs(yc+1)
        const int yc = r - 2;
        const float psum = hs2 + hs1 + hs;
        hs2 = hs1; hs1 = hs;

        const bool row3 = (yc != 0) & (yc != HGT - 1);  // rowcnt==3 ?
        // bin = floor(psum / cnt / BIN_W) == floor(psum * (15/cnt)), cnt in {4,6,9}
        const float c2b = row3 ? (col3 ? (15.0f / 9.0f) : 2.5f)
                               : (col3 ? 2.5f : 3.75f);
        int b = (int)(psum * c2b);
        b = b < 0 ? 0 : (b > NUM_BINS - 1 ? NUM_BINS - 1 : b);
        const bool pos = lab2 > 0.5f;
        lab2 = lab1; lab1 = lb;

        const bool doemit = elane & (it >= 4);
        const unsigned long long posm = __ballot(doemit & pos);
        #pragma unroll
        for (int bb = 0; bb < NUM_BINS; ++bb) {
            unsigned long long m = __ballot(doemit & (b == bb));
            ccnt[bb] += (unsigned int)__popcll(m);
            pcnt[bb] += (unsigned int)__popcll(m & posm);
        }
    }

    // per-block reduction, then one set of global atomics per block
    if (lane == 0) {
        #pragma unroll
        for (int b = 0; b < NUM_BINS; ++b) {
            if (ccnt[b]) atomicAdd(&sh[b], ccnt[b]);
            if (pcnt[b]) atomicAdd(&sh[NUM_BINS + b], pcnt[b]);
        }
    }
    __syncthreads();
    if (tid < 2 * NUM_BINS) {
        unsigned int v = sh[tid];
        if (v) atomicAdd(&hist[tid], v);
    }
}

// ---------------------------------------------------------------------------
// Kernel 2: bin_freqs + gather for target pixels (bit-exact round-0 path).
// grid = HW/4/256 = 256 blocks, float4.
// ---------------------------------------------------------------------------
__global__ __launch_bounds__(256) void k_out(const float4* __restrict__ tl,
                                             const unsigned int* __restrict__ hist,
                                             float4* __restrict__ out) {
    __shared__ float s_f[NUM_BINS];
    const float BIN_W = (float)(1.0 / 15.0);
    int tid = threadIdx.x;
    if (tid < NUM_BINS) {
        unsigned int c = hist[tid];
        unsigned int p = hist[NUM_BINS + tid];
        s_f[tid] = (c > 0u) ? (float)p / (float)c : 0.0f;
    }
    __syncthreads();
    int i = blockIdx.x * 256 + tid;
    float4 t = tl[i];
    float4 o;
    {
        float pr = 1.0f / (1.0f + expf(-t.x));
        int b = (int)(pr / BIN_W); b = b < 0 ? 0 : (b > NUM_BINS - 1 ? NUM_BINS - 1 : b);
        o.x = s_f[b];
    }
    {
        float pr = 1.0f / (1.0f + expf(-t.y));
        int b = (int)(pr / BIN_W); b = b < 0 ? 0 : (b > NUM_BINS - 1 ? NUM_BINS - 1 : b);
        o.y = s_f[b];
    }
    {
        float pr = 1.0f / (1.0f + expf(-t.z));
        int b = (int)(pr / BIN_W); b = b < 0 ? 0 : (b > NUM_BINS - 1 ? NUM_BINS - 1 : b);
        o.z = s_f[b];
    }
    {
        float pr = 1.0f / (1.0f + expf(-t.w));
        int b = (int)(pr / BIN_W); b = b < 0 ? 0 : (b > NUM_BINS - 1 ? NUM_BINS - 1 : b);
        o.w = s_f[b];
    }
    out[i] = o;
}

extern "C" void kernel_launch(void* const* d_in, const int* in_sizes, int n_in,
                              void* d_out, int out_size, void* d_ws, size_t ws_size,
                              hipStream_t stream) {
    const float* imgs  = (const float*)d_in[0];  // [1,32,3,512,512]
    const float* labs  = (const float*)d_in[1];  // [1,32,1,512,512]
    const float* tlog  = (const float*)d_in[2];  // [1,1,512,512]
    const float* w_img = (const float*)d_in[3];  // [1,3,3,3]
    const float* w_lab = (const float*)d_in[4];  // [1,1,3,3]
    float* out = (float*)d_out;

    float* sumLab = (float*)d_ws;                                       // HW floats
    unsigned int* hist = (unsigned int*)((char*)d_ws + (size_t)HW * sizeof(float));

    k_sumlab<<<HW / 4 / 256, 256, 0, stream>>>((const float4*)labs, (float4*)sumLab, hist);

    k_main<<<TOTAL_UNITS / 4, 256, 0, stream>>>(imgs, labs, sumLab, w_img, w_lab, hist);

    k_out<<<HW / 4 / 256, 256, 0, stream>>>((const float4*)tlog, hist, (float4*)out);
}

// Round 5
// 205.185 us; speedup vs baseline: 1.4859x; 1.0770x over previous
//
#include <hip/hip_runtime.h>
#include <hip/hip_bf16.h>

#define NUM_BINS 15
#define N_CTX 32
#define C_IMG 3
#define HGT 512
#define WID 512
#define HW (HGT * WID)

#define SEG 16                       // emitted rows per wave-unit
#define NSEG (HGT / SEG)             // 32
#define UNITS (N_CTX * NSEG)         // 1024 waves = 1/SIMD, 256 blocks = 1/CU

// ---------------------------------------------------------------------------
// Kernel 0: sumLab = sum_n labs[n]; zero the global histogram. float4 loads.
// ---------------------------------------------------------------------------
__global__ __launch_bounds__(256) void k_sumlab(const float4* __restrict__ labs,
                                                float4* __restrict__ sumLab,
                                                unsigned int* __restrict__ hist) {
    int i = blockIdx.x * 256 + threadIdx.x;
    if (blockIdx.x == 0 && threadIdx.x < 2 * NUM_BINS) hist[threadIdx.x] = 0u;
    float4 s = make_float4(0.f, 0.f, 0.f, 0.f);
    #pragma unroll
    for (int n = 0; n < N_CTX; ++n) {
        float4 v = labs[(size_t)n * (HW / 4) + i];
        s.x += v.x; s.y += v.y; s.z += v.z; s.w += v.w;
    }
    sumLab[i] = s;
}

// ---------------------------------------------------------------------------
// Kernel 1: streaming conv -> sigmoid -> 3x3 valid-count pool -> histogram.
// One wave per (n, seg); each lane owns 8 contiguous columns (64*8 = 512 =
// full row). grid = 256 blocks x 256 thr = 1 block/CU, 1 wave/SIMD exactly.
// ---------------------------------------------------------------------------
__global__ __launch_bounds__(256, 1) void k_main(const float* __restrict__ imgs,
                                                 const float* __restrict__ labs,
                                                 const float* __restrict__ sumLab,
                                                 const float* __restrict__ w_img,
                                                 const float* __restrict__ w_lab,
                                                 unsigned int* __restrict__ hist) {
    __shared__ unsigned int sh[2 * NUM_BINS];
    const int tid  = threadIdx.x;
    const int lane = tid & 63;
    const int u    = blockIdx.x * 4 + (tid >> 6);
    const int n    = u >> 5;             // u / NSEG
    const int seg  = u & (NSEG - 1);     // u % NSEG
    const int y0   = seg * SEG;
    const int x0   = lane * 8;
    const float inv31 = 1.0f / 31.0f;
    const bool l0  = (lane == 0);
    const bool l63 = (lane == 63);

    if (tid < 2 * NUM_BINS) sh[tid] = 0u;
    __syncthreads();

    // 3x3 weights, 4 planes (img0..2, loo) — uniform -> scalarized
    float w[4][3][3];
    #pragma unroll
    for (int c = 0; c < 3; ++c)
        #pragma unroll
        for (int i = 0; i < 3; ++i)
            #pragma unroll
            for (int j = 0; j < 3; ++j)
                w[c][i][j] = w_img[c * 9 + i * 3 + j];
    #pragma unroll
    for (int i = 0; i < 3; ++i)
        #pragma unroll
        for (int j = 0; j < 3; ++j)
            w[3][i][j] = w_lab[i * 3 + j];

    const float* pi0 = imgs + (size_t)n * C_IMG * HW + x0;
    const float* pi1 = pi0 + HW;
    const float* pi2 = pi0 + 2 * HW;
    const float* pla = labs + (size_t)n * HW + x0;
    const float* psu = sumLab + x0;

    // register rings (8-wide)
    float hA2[8], hA1[8], hB1[8], hs2[8], hs1[8], la1[8], la2[8];
    #pragma unroll
    for (int c = 0; c < 8; ++c) {
        hA2[c] = hA1[c] = hB1[c] = 0.f;
        hs2[c] = hs1[c] = 0.f;
        la1[c] = la2[c] = 0.f;
    }
    // byte-packed per-lane histograms: 15 bins x 8 bits (max 128 items/lane)
    unsigned int accC[4] = {0u, 0u, 0u, 0u};
    unsigned int accP[4] = {0u, 0u, 0u, 0u};

    #pragma unroll 2
    for (int it = 0; it < SEG + 4; ++it) {
        const int r = y0 - 2 + it;
        float4 A0, B0, A1, B1, A2, B2, AL, BL, AS, BS;
        if (r >= 0 && r < HGT) {
            const size_t ro = (size_t)r * WID;
            A0 = *reinterpret_cast<const float4*>(pi0 + ro);
            B0 = *reinterpret_cast<const float4*>(pi0 + ro + 4);
            A1 = *reinterpret_cast<const float4*>(pi1 + ro);
            B1 = *reinterpret_cast<const float4*>(pi1 + ro + 4);
            A2 = *reinterpret_cast<const float4*>(pi2 + ro);
            B2 = *reinterpret_cast<const float4*>(pi2 + ro + 4);
            AL = *reinterpret_cast<const float4*>(pla + ro);
            BL = *reinterpret_cast<const float4*>(pla + ro + 4);
            AS = *reinterpret_cast<const float4*>(psu + ro);
            BS = *reinterpret_cast<const float4*>(psu + ro + 4);
        } else {
            const float4 z4 = make_float4(0.f, 0.f, 0.f, 0.f);
            A0 = B0 = A1 = B1 = A2 = B2 = AL = BL = AS = BS = z4;
        }

        // per-plane 10-wide value vectors (left halo, 8 own, right halo)
        float v[4][10];
        v[0][1] = A0.x; v[0][2] = A0.y; v[0][3] = A0.z; v[0][4] = A0.w;
        v[0][5] = B0.x; v[0][6] = B0.y; v[0][7] = B0.z; v[0][8] = B0.w;
        v[1][1] = A1.x; v[1][2] = A1.y; v[1][3] = A1.z; v[1][4] = A1.w;
        v[1][5] = B1.x; v[1][6] = B1.y; v[1][7] = B1.z; v[1][8] = B1.w;
        v[2][1] = A2.x; v[2][2] = A2.y; v[2][3] = A2.z; v[2][4] = A2.w;
        v[2][5] = B2.x; v[2][6] = B2.y; v[2][7] = B2.z; v[2][8] = B2.w;
        v[3][1] = (AS.x - AL.x) * inv31;
        v[3][2] = (AS.y - AL.y) * inv31;
        v[3][3] = (AS.z - AL.z) * inv31;
        v[3][4] = (AS.w - AL.w) * inv31;
        v[3][5] = (BS.x - BL.x) * inv31;
        v[3][6] = (BS.y - BL.y) * inv31;
        v[3][7] = (BS.z - BL.z) * inv31;
        v[3][8] = (BS.w - BL.w) * inv31;
        #pragma unroll
        for (int p = 0; p < 4; ++p) {
            float lft = __shfl_up(v[p][8], 1);
            float rgt = __shfl_down(v[p][1], 1);
            v[p][0] = l0  ? 0.f : lft;
            v[p][9] = l63 ? 0.f : rgt;
        }

        // horizontal 3-tap per kernel-row, accumulated over planes
        float h0[8], h1[8], h2[8];
        #pragma unroll
        for (int c = 0; c < 8; ++c) { h0[c] = 0.f; h1[c] = 0.f; h2[c] = 0.f; }
        #pragma unroll
        for (int p = 0; p < 4; ++p)
            #pragma unroll
            for (int c = 0; c < 8; ++c) {
                h0[c] += w[p][0][0] * v[p][c] + w[p][0][1] * v[p][c + 1] + w[p][0][2] * v[p][c + 2];
                h1[c] += w[p][1][0] * v[p][c] + w[p][1][1] * v[p][c + 1] + w[p][1][2] * v[p][c + 2];
                h2[c] += w[p][2][0] * v[p][c] + w[p][2][1] * v[p][c + 1] + w[p][2][2] * v[p][c + 2];
            }

        // z(y=r-1) = h0(r-2) + h1(r-1) + h2(r); sigmoid; zero outside image
        const int y = r - 1;
        const bool yv = (y >= 0) & (y < HGT);
        float pc_[8];
        #pragma unroll
        for (int c = 0; c < 8; ++c) {
            float z = hA2[c] + hB1[c] + h2[c];
            float pr = 1.0f / (1.0f + __expf(-z));
            pc_[c] = yv ? pr : 0.f;
        }
        #pragma unroll
        for (int c = 0; c < 8; ++c) { hA2[c] = hA1[c]; hA1[c] = h0[c]; hB1[c] = h1[c]; }

        // horizontal pool sums
        float hsv[8];
        {
            float lft = __shfl_up(pc_[7], 1);
            float rgt = __shfl_down(pc_[0], 1);
            float pl_ = l0  ? 0.f : lft;
            float pr_ = l63 ? 0.f : rgt;
            hsv[0] = pl_ + pc_[0] + pc_[1];
            #pragma unroll
            for (int c = 1; c < 7; ++c) hsv[c] = pc_[c - 1] + pc_[c] + pc_[c + 1];
            hsv[7] = pc_[6] + pc_[7] + pr_;
        }

        // emit pooled row yc = r-2 (uniform branch; all 512 cols valid)
        if (it >= 4) {
            const int yc = r - 2;
            const bool row3 = (yc != 0) & (yc != HGT - 1);
            const float cbi = row3 ? (15.0f / 9.0f) : 2.5f;   // 15/cnt
            const float cbe = row3 ? 2.5f : 3.75f;
            const float cb0 = l0  ? cbe : cbi;
            const float cb7 = l63 ? cbe : cbi;
            #pragma unroll
            for (int c = 0; c < 8; ++c) {
                const float psum = hs2[c] + hs1[c] + hsv[c];
                const float cb = (c == 0) ? cb0 : ((c == 7) ? cb7 : cbi);
                int b = (int)(psum * cb);
                b = b > NUM_BINS - 1 ? NUM_BINS - 1 : b;
                const unsigned int inc = 1u << ((b & 3) << 3);
                const int rs = b >> 2;
                const bool pos = la2[c] > 0.5f;
                const unsigned int incp = pos ? inc : 0u;
                #pragma unroll
                for (int k = 0; k < 4; ++k) {
                    const bool m = (rs == k);
                    accC[k] += m ? inc : 0u;
                    accP[k] += m ? incp : 0u;
                }
            }
        }

        // ring updates (pool + label)
        #pragma unroll
        for (int c = 0; c < 8; ++c) { hs2[c] = hs1[c]; hs1[c] = hsv[c]; }
        la2[0] = la1[0]; la2[1] = la1[1]; la2[2] = la1[2]; la2[3] = la1[3];
        la2[4] = la1[4]; la2[5] = la1[5]; la2[6] = la1[6]; la2[7] = la1[7];
        la1[0] = AL.x; la1[1] = AL.y; la1[2] = AL.z; la1[3] = AL.w;
        la1[4] = BL.x; la1[5] = BL.y; la1[6] = BL.z; la1[7] = BL.w;
    }

    // flush: unpack bytes, wave-reduce, one LDS atomic set per wave
    #pragma unroll
    for (int b = 0; b < NUM_BINS; ++b) {
        unsigned int c = (accC[b >> 2] >> ((b & 3) * 8)) & 0xffu;
        unsigned int p = (accP[b >> 2] >> ((b & 3) * 8)) & 0xffu;
        #pragma unroll
        for (int off = 1; off < 64; off <<= 1) {
            c += __shfl_xor(c, off);
            p += __shfl_xor(p, off);
        }
        if (lane == 0) {
            atomicAdd(&sh[b], c);
            atomicAdd(&sh[NUM_BINS + b], p);
        }
    }
    __syncthreads();
    if (tid < 2 * NUM_BINS) {
        unsigned int v = sh[tid];
        if (v) atomicAdd(&hist[tid], v);
    }
}

// ---------------------------------------------------------------------------
// Kernel 2: bin_freqs + gather for target pixels (bit-exact path).
// ---------------------------------------------------------------------------
__global__ __launch_bounds__(256) void k_out(const float4* __restrict__ tl,
                                             const unsigned int* __restrict__ hist,
                                             float4* __restrict__ out) {
    __shared__ float s_f[NUM_BINS];
    const float BIN_W = (float)(1.0 / 15.0);
    int tid = threadIdx.x;
    if (tid < NUM_BINS) {
        unsigned int c = hist[tid];
        unsigned int p = hist[NUM_BINS + tid];
        s_f[tid] = (c > 0u) ? (float)p / (float)c : 0.0f;
    }
    __syncthreads();
    int i = blockIdx.x * 256 + tid;
    float4 t = tl[i];
    float4 o;
    {
        float pr = 1.0f / (1.0f + expf(-t.x));
        int b = (int)(pr / BIN_W); b = b < 0 ? 0 : (b > NUM_BINS - 1 ? NUM_BINS - 1 : b);
        o.x = s_f[b];
    }
    {
        float pr = 1.0f / (1.0f + expf(-t.y));
        int b = (int)(pr / BIN_W); b = b < 0 ? 0 : (b > NUM_BINS - 1 ? NUM_BINS - 1 : b);
        o.y = s_f[b];
    }
    {
        float pr = 1.0f / (1.0f + expf(-t.z));
        int b = (int)(pr / BIN_W); b = b < 0 ? 0 : (b > NUM_BINS - 1 ? NUM_BINS - 1 : b);
        o.z = s_f[b];
    }
    {
        float pr = 1.0f / (1.0f + expf(-t.w));
        int b = (int)(pr / BIN_W); b = b < 0 ? 0 : (b > NUM_BINS - 1 ? NUM_BINS - 1 : b);
        o.w = s_f[b];
    }
    out[i] = o;
}

extern "C" void kernel_launch(void* const* d_in, const int* in_sizes, int n_in,
                              void* d_out, int out_size, void* d_ws, size_t ws_size,
                              hipStream_t stream) {
    const float* imgs  = (const float*)d_in[0];  // [1,32,3,512,512]
    const float* labs  = (const float*)d_in[1];  // [1,32,1,512,512]
    const float* tlog  = (const float*)d_in[2];  // [1,1,512,512]
    const float* w_img = (const float*)d_in[3];  // [1,3,3,3]
    const float* w_lab = (const float*)d_in[4];  // [1,1,3,3]
    float* out = (float*)d_out;

    float* sumLab = (float*)d_ws;                                       // HW floats
    unsigned int* hist = (unsigned int*)((char*)d_ws + (size_t)HW * sizeof(float));

    k_sumlab<<<HW / 4 / 256, 256, 0, stream>>>((const float4*)labs, (float4*)sumLab, hist);

    k_main<<<UNITS / 4, 256, 0, stream>>>(imgs, labs, sumLab, w_img, w_lab, hist);

    k_out<<<HW / 4 / 256, 256, 0, stream>>>((const float4*)tlog, hist, (float4*)out);
}

// Round 10
// 202.682 us; speedup vs baseline: 1.5042x; 1.0123x over previous
//
#include <hip/hip_runtime.h>
#include <hip/hip_bf16.h>

#define NUM_BINS 15
#define N_CTX 32
#define C_IMG 3
#define HGT 512
#define WID 512
#define HW (HGT * WID)

#define SEG 8                        // emitted rows per wave-unit
#define NSEG (HGT / SEG)             // 64
#define UNITS (N_CTX * NSEG)         // 2048 waves = 2/SIMD, 512 blocks = 2/CU

// ---------------------------------------------------------------------------
// Kernel 0: sumLab = sum_n labs[n]; zero the global histogram. float4 loads.
// ---------------------------------------------------------------------------
__global__ __launch_bounds__(256) void k_sumlab(const float4* __restrict__ labs,
                                                float4* __restrict__ sumLab,
                                                unsigned int* __restrict__ hist) {
    int i = blockIdx.x * 256 + threadIdx.x;
    if (blockIdx.x == 0 && threadIdx.x < 2 * NUM_BINS) hist[threadIdx.x] = 0u;
    float4 s = make_float4(0.f, 0.f, 0.f, 0.f);
    #pragma unroll
    for (int n = 0; n < N_CTX; ++n) {
        float4 v = labs[(size_t)n * (HW / 4) + i];
        s.x += v.x; s.y += v.y; s.z += v.z; s.w += v.w;
    }
    sumLab[i] = s;
}

// row loader: unconditional, row-clamped (mask applied at use site)
__device__ __forceinline__ void load_row(const float* pi0, const float* pi1,
                                         const float* pi2, const float* pla,
                                         const float* psu, int r, float4 R[10]) {
    const int rc = r < 0 ? 0 : (r > HGT - 1 ? HGT - 1 : r);
    const size_t ro = (size_t)rc * WID;
    R[0] = *reinterpret_cast<const float4*>(pi0 + ro);
    R[1] = *reinterpret_cast<const float4*>(pi0 + ro + 4);
    R[2] = *reinterpret_cast<const float4*>(pi1 + ro);
    R[3] = *reinterpret_cast<const float4*>(pi1 + ro + 4);
    R[4] = *reinterpret_cast<const float4*>(pi2 + ro);
    R[5] = *reinterpret_cast<const float4*>(pi2 + ro + 4);
    R[6] = *reinterpret_cast<const float4*>(pla + ro);
    R[7] = *reinterpret_cast<const float4*>(pla + ro + 4);
    R[8] = *reinterpret_cast<const float4*>(psu + ro);
    R[9] = *reinterpret_cast<const float4*>(psu + ro + 4);
}

// ---------------------------------------------------------------------------
// Kernel 1: streaming conv -> sigmoid -> 3x3 valid-count pool -> histogram.
// One wave per (n, seg); each lane owns 8 contiguous columns (full 512 row).
// Next-row prefetch double-buffer; 512 blocks = 2 blocks/CU, 2 waves/SIMD.
// ---------------------------------------------------------------------------
__global__ __launch_bounds__(256, 2) void k_main(const float* __restrict__ imgs,
                                                 const float* __restrict__ labs,
                                                 const float* __restrict__ sumLab,
                                                 const float* __restrict__ w_img,
                                                 const float* __restrict__ w_lab,
                                                 unsigned int* __restrict__ hist) {
    __shared__ unsigned int sh[2 * NUM_BINS];
    const int tid  = threadIdx.x;
    const int lane = tid & 63;
    const int u    = blockIdx.x * 4 + (tid >> 6);
    const int n    = u >> 6;             // u / NSEG
    const int seg  = u & (NSEG - 1);     // u % NSEG
    const int y0   = seg * SEG;
    const int x0   = lane * 8;
    const float inv31 = 1.0f / 31.0f;
    const bool l0  = (lane == 0);
    const bool l63 = (lane == 63);

    if (tid < 2 * NUM_BINS) sh[tid] = 0u;
    __syncthreads();

    // 3x3 weights, 4 planes (img0..2, loo) — uniform -> scalarized
    float w[4][3][3];
    #pragma unroll
    for (int c = 0; c < 3; ++c)
        #pragma unroll
        for (int i = 0; i < 3; ++i)
            #pragma unroll
            for (int j = 0; j < 3; ++j)
                w[c][i][j] = w_img[c * 9 + i * 3 + j];
    #pragma unroll
    for (int i = 0; i < 3; ++i)
        #pragma unroll
        for (int j = 0; j < 3; ++j)
            w[3][i][j] = w_lab[i * 3 + j];

    const float* pi0 = imgs + (size_t)n * C_IMG * HW + x0;
    const float* pi1 = pi0 + HW;
    const float* pi2 = pi0 + 2 * HW;
    const float* pla = labs + (size_t)n * HW + x0;
    const float* psu = sumLab + x0;

    // register rings (8-wide)
    float hA2[8], hA1[8], hB1[8], hs2[8], hs1[8], la1[8], la2[8];
    #pragma unroll
    for (int c = 0; c < 8; ++c) {
        hA2[c] = hA1[c] = hB1[c] = 0.f;
        hs2[c] = hs1[c] = 0.f;
        la1[c] = la2[c] = 0.f;
    }
    // byte-packed per-lane histograms: 15 bins x 8 bits (max 64 items/lane)
    unsigned int accC[4] = {0u, 0u, 0u, 0u};
    unsigned int accP[4] = {0u, 0u, 0u, 0u};

    float4 C[10];
    load_row(pi0, pi1, pi2, pla, psu, y0 - 2, C);

    #pragma unroll 2
    for (int it = 0; it < SEG + 4; ++it) {
        const int r = y0 - 2 + it;

        // ---- prefetch next row FIRST (latency hidden under this iteration) ----
        float4 P[10];
        load_row(pi0, pi1, pi2, pla, psu, r + 1, P);

        const float m = (r >= 0 && r < HGT) ? 1.0f : 0.0f;   // wave-uniform
        const float inv31m = inv31 * m;

        // per-plane 10-wide value vectors (left halo, 8 own, right halo)
        float v[4][10];
        v[0][1] = C[0].x * m; v[0][2] = C[0].y * m; v[0][3] = C[0].z * m; v[0][4] = C[0].w * m;
        v[0][5] = C[1].x * m; v[0][6] = C[1].y * m; v[0][7] = C[1].z * m; v[0][8] = C[1].w * m;
        v[1][1] = C[2].x * m; v[1][2] = C[2].y * m; v[1][3] = C[2].z * m; v[1][4] = C[2].w * m;
        v[1][5] = C[3].x * m; v[1][6] = C[3].y * m; v[1][7] = C[3].z * m; v[1][8] = C[3].w * m;
        v[2][1] = C[4].x * m; v[2][2] = C[4].y * m; v[2][3] = C[4].z * m; v[2][4] = C[4].w * m;
        v[2][5] = C[5].x * m; v[2][6] = C[5].y * m; v[2][7] = C[5].z * m; v[2][8] = C[5].w * m;
        v[3][1] = (C[8].x - C[6].x) * inv31m;
        v[3][2] = (C[8].y - C[6].y) * inv31m;
        v[3][3] = (C[8].z - C[6].z) * inv31m;
        v[3][4] = (C[8].w - C[6].w) * inv31m;
        v[3][5] = (C[9].x - C[7].x) * inv31m;
        v[3][6] = (C[9].y - C[7].y) * inv31m;
        v[3][7] = (C[9].z - C[7].z) * inv31m;
        v[3][8] = (C[9].w - C[7].w) * inv31m;
        #pragma unroll
        for (int p = 0; p < 4; ++p) {
            float lft = __shfl_up(v[p][8], 1);
            float rgt = __shfl_down(v[p][1], 1);
            v[p][0] = l0  ? 0.f : lft;
            v[p][9] = l63 ? 0.f : rgt;
        }

        // horizontal 3-tap per kernel-row, accumulated over planes
        float h0[8], h1[8], h2[8];
        #pragma unroll
        for (int c = 0; c < 8; ++c) { h0[c] = 0.f; h1[c] = 0.f; h2[c] = 0.f; }
        #pragma unroll
        for (int p = 0; p < 4; ++p)
            #pragma unroll
            for (int c = 0; c < 8; ++c) {
                h0[c] += w[p][0][0] * v[p][c] + w[p][0][1] * v[p][c + 1] + w[p][0][2] * v[p][c + 2];
                h1[c] += w[p][1][0] * v[p][c] + w[p][1][1] * v[p][c + 1] + w[p][1][2] * v[p][c + 2];
                h2[c] += w[p][2][0] * v[p][c] + w[p][2][1] * v[p][c + 1] + w[p][2][2] * v[p][c + 2];
            }

        // z(y=r-1) = h0(r-2) + h1(r-1) + h2(r); sigmoid; zero outside image
        const int y = r - 1;
        const bool yv = (y >= 0) & (y < HGT);
        float pc_[8];
        #pragma unroll
        for (int c = 0; c < 8; ++c) {
            float z = hA2[c] + hB1[c] + h2[c];
            float pr = 1.0f / (1.0f + __expf(-z));
            pc_[c] = yv ? pr : 0.f;
        }
        #pragma unroll
        for (int c = 0; c < 8; ++c) { hA2[c] = hA1[c]; hA1[c] = h0[c]; hB1[c] = h1[c]; }

        // horizontal pool sums
        float hsv[8];
        {
            float lft = __shfl_up(pc_[7], 1);
            float rgt = __shfl_down(pc_[0], 1);
            float pl_ = l0  ? 0.f : lft;
            float pr_ = l63 ? 0.f : rgt;
            hsv[0] = pl_ + pc_[0] + pc_[1];
            #pragma unroll
            for (int c = 1; c < 7; ++c) hsv[c] = pc_[c - 1] + pc_[c] + pc_[c + 1];
            hsv[7] = pc_[6] + pc_[7] + pr_;
        }

        // emit pooled row yc = r-2 (uniform branch; all 512 cols valid)
        if (it >= 4) {
            const int yc = r - 2;
            const bool row3 = (yc != 0) & (yc != HGT - 1);
            const float cbi = row3 ? (15.0f / 9.0f) : 2.5f;   // 15/cnt
            const float cbe = row3 ? 2.5f : 3.75f;
            const float cb0 = l0  ? cbe : cbi;
            const float cb7 = l63 ? cbe : cbi;
            #pragma unroll
            for (int c = 0; c < 8; ++c) {
                const float psum = hs2[c] + hs1[c] + hsv[c];
                const float cb = (c == 0) ? cb0 : ((c == 7) ? cb7 : cbi);
                int b = (int)(psum * cb);
                b = b > NUM_BINS - 1 ? NUM_BINS - 1 : b;
                const unsigned int inc = 1u << ((b & 3) << 3);
                const int rs = b >> 2;
                const bool pos = la2[c] > 0.5f;
                const unsigned int incp = pos ? inc : 0u;
                #pragma unroll
                for (int k = 0; k < 4; ++k) {
                    const bool mm = (rs == k);
                    accC[k] += mm ? inc : 0u;
                    accP[k] += mm ? incp : 0u;
                }
            }
        }

        // ring updates (pool + label, label masked by row validity)
        #pragma unroll
        for (int c = 0; c < 8; ++c) { hs2[c] = hs1[c]; hs1[c] = hsv[c]; la2[c] = la1[c]; }
        la1[0] = C[6].x * m; la1[1] = C[6].y * m; la1[2] = C[6].z * m; la1[3] = C[6].w * m;
        la1[4] = C[7].x * m; la1[5] = C[7].y * m; la1[6] = C[7].z * m; la1[7] = C[7].w * m;

        // rotate prefetch buffer
        #pragma unroll
        for (int q = 0; q < 10; ++q) C[q] = P[q];
    }

    // flush: unpack bytes, wave-reduce, one LDS atomic set per wave
    #pragma unroll
    for (int b = 0; b < NUM_BINS; ++b) {
        unsigned int c = (accC[b >> 2] >> ((b & 3) * 8)) & 0xffu;
        unsigned int p = (accP[b >> 2] >> ((b & 3) * 8)) & 0xffu;
        #pragma unroll
        for (int off = 1; off < 64; off <<= 1) {
            c += __shfl_xor(c, off);
            p += __shfl_xor(p, off);
        }
        if (lane == 0) {
            atomicAdd(&sh[b], c);
            atomicAdd(&sh[NUM_BINS + b], p);
        }
    }
    __syncthreads();
    if (tid < 2 * NUM_BINS) {
        unsigned int vsum = sh[tid];
        if (vsum) atomicAdd(&hist[tid], vsum);
    }
}

// ---------------------------------------------------------------------------
// Kernel 2: bin_freqs + gather for target pixels (bit-exact path).
// ---------------------------------------------------------------------------
__global__ __launch_bounds__(256) void k_out(const float4* __restrict__ tl,
                                             const unsigned int* __restrict__ hist,
                                             float4* __restrict__ out) {
    __shared__ float s_f[NUM_BINS];
    const float BIN_W = (float)(1.0 / 15.0);
    int tid = threadIdx.x;
    if (tid < NUM_BINS) {
        unsigned int c = hist[tid];
        unsigned int p = hist[NUM_BINS + tid];
        s_f[tid] = (c > 0u) ? (float)p / (float)c : 0.0f;
    }
    __syncthreads();
    int i = blockIdx.x * 256 + tid;
    float4 t = tl[i];
    float4 o;
    {
        float pr = 1.0f / (1.0f + expf(-t.x));
        int b = (int)(pr / BIN_W); b = b < 0 ? 0 : (b > NUM_BINS - 1 ? NUM_BINS - 1 : b);
        o.x = s_f[b];
    }
    {
        float pr = 1.0f / (1.0f + expf(-t.y));
        int b = (int)(pr / BIN_W); b = b < 0 ? 0 : (b > NUM_BINS - 1 ? NUM_BINS - 1 : b);
        o.y = s_f[b];
    }
    {
        float pr = 1.0f / (1.0f + expf(-t.z));
        int b = (int)(pr / BIN_W); b = b < 0 ? 0 : (b > NUM_BINS - 1 ? NUM_BINS - 1 : b);
        o.z = s_f[b];
    }
    {
        float pr = 1.0f / (1.0f + expf(-t.w));
        int b = (int)(pr / BIN_W); b = b < 0 ? 0 : (b > NUM_BINS - 1 ? NUM_BINS - 1 : b);
        o.w = s_f[b];
    }
    out[i] = o;
}

extern "C" void kernel_launch(void* const* d_in, const int* in_sizes, int n_in,
                              void* d_out, int out_size, void* d_ws, size_t ws_size,
                              hipStream_t stream) {
    const float* imgs  = (const float*)d_in[0];  // [1,32,3,512,512]
    const float* labs  = (const float*)d_in[1];  // [1,32,1,512,512]
    const float* tlog  = (const float*)d_in[2];  // [1,1,512,512]
    const float* w_img = (const float*)d_in[3];  // [1,3,3,3]
    const float* w_lab = (const float*)d_in[4];  // [1,1,3,3]
    float* out = (float*)d_out;

    float* sumLab = (float*)d_ws;                                       // HW floats
    unsigned int* hist = (unsigned int*)((char*)d_ws + (size_t)HW * sizeof(float));

    k_sumlab<<<HW / 4 / 256, 256, 0, stream>>>((const float4*)labs, (float4*)sumLab, hist);

    k_main<<<UNITS / 4, 256, 0, stream>>>(imgs, labs, sumLab, w_img, w_lab, hist);

    k_out<<<HW / 4 / 256, 256, 0, stream>>>((const float4*)tlog, hist, (float4*)out);
}